// Round 4
// baseline (154.575 us; speedup 1.0000x reference)
//
#include <hip/hip_runtime.h>
#include <math.h>

#define NTOK   16384
#define HDIM   1024
#define HHALF  512
#define NE     16

// d_out layout (concatenated reference outputs, all f32; indices stored as float)
#define OFF_TP  0
#define OFF_TI  (NTOK * 2)
#define OFF_DEC (NTOK * 4)
#define OFF_PH  (OFF_DEC + NTOK * NE)
#define OFF_PR  (OFF_PH + NTOK * NE)

typedef _Float16 half8 __attribute__((ext_vector_type(8)));
typedef _Float16 half4 __attribute__((ext_vector_type(4)));
typedef float f32x16 __attribute__((ext_vector_type(16)));
typedef float f32x4 __attribute__((ext_vector_type(4)));

#define LO_SCALE     2048.0f
#define LO_SCALE_INV (1.0f / 2048.0f)
#define MFMA32(a,b,c) __builtin_amdgcn_mfma_f32_32x32x16_f16(a,b,c,0,0,0)
#define MFMA16(a,b,c) __builtin_amdgcn_mfma_f32_16x16x32_f16(a,b,c,0,0,0)

// Raw barrier: LDS visibility + read-WAR safety via lgkmcnt(0), but NO vmcnt
// drain -- global loads stay in flight across the barrier (T4).
#define BAR() asm volatile("s_waitcnt lgkmcnt(0)\n\ts_barrier" ::: "memory")

__device__ __forceinline__ float gelu_exact(float x) {
    return 0.5f * x * (1.0f + erff(x * 0.70710678118654752440f));
}

__device__ __forceinline__ void cvt_split(float4 v, half4& hi, half4& lo) {
    _Float16 h0 = (_Float16)v.x, h1 = (_Float16)v.y,
             h2 = (_Float16)v.z, h3 = (_Float16)v.w;
    hi = (half4){h0, h1, h2, h3};
    lo = (half4){(_Float16)((v.x - (float)h0) * LO_SCALE),
                 (_Float16)((v.y - (float)h1) * LO_SCALE),
                 (_Float16)((v.z - (float)h2) * LO_SCALE),
                 (_Float16)((v.w - (float)h3) * LO_SCALE)};
}

// A-LDS swizzle: plane-internal offset for row r (16B granules),
// XOR row bits 3-4 into byte bits 5-6 -> lanes 0,8,16,24 hit distinct banks.
__device__ __forceinline__ int aswz(int r) { return (r * 16) ^ ((r & 24) << 2); }

// ---------------------------------------------------------------------------
// Prologue: build register-fragment B image in ws AND zero the PH/PR raw-sum
// accumulation regions of d_out (gemm blocks atomicAdd into them).
// Image (f16 elems): addr16 = 8*u where u = ((((ph*32+kc)*8+sl)*8+f)*64+l);
// f = nf*4 + kh*2 + pl. Value: col = sl*64+nf*32+(l&31),
// k = kc*32+kh*16+(l>>5)*8+j; pl=0 -> f16(W[k][col]), pl=1 -> (W-hi)*2048.
// ---------------------------------------------------------------------------
__global__ void __launch_bounds__(256)
qir_wtrans(const float* __restrict__ w1a, const float* __restrict__ w1p,
           _Float16* __restrict__ wt, float* __restrict__ out)
{
    int u = blockIdx.x * 256 + threadIdx.x;   // 0..262143
    out[OFF_PH + u] = 0.0f;
    out[OFF_PH + 262144 + u] = 0.0f;

    int l  = u & 63;
    int f  = (u >> 6) & 7;
    int sl = (u >> 9) & 7;
    int kc = (u >> 12) & 31;
    int ph = u >> 17;
    int nf = f >> 2, kh = (f >> 1) & 1, pl = f & 1;
    int col = sl * 64 + nf * 32 + (l & 31);
    int k0  = kc * 32 + kh * 16 + (l >> 5) * 8;
    const float* __restrict__ W = ph ? w1p : w1a;
    half8 v;
    #pragma unroll
    for (int j = 0; j < 8; ++j) {
        float x = W[(size_t)(k0 + j) * HHALF + col];
        _Float16 h = (_Float16)x;
        v[j] = pl ? (_Float16)((x - (float)h) * LO_SCALE) : h;
    }
    *(half8*)&wt[(size_t)u * 8] = v;
}

// ---------------------------------------------------------------------------
// Main GEMM: block = 128 tokens x 256 cols x one phase. B frags global->reg
// (L2-resident), A staged in 2x16KB LDS (swizzled), counted-wait schedule:
// loads issued at top of kstep survive the barrier; only lgkm drains.
// ---------------------------------------------------------------------------
__device__ __forceinline__ void kstep(
    int kc, const float* __restrict__ aptr, const _Float16* __restrict__ bptr,
    char* Acur, char* Anxt, int a_rd, int a_off0, int a_off1,
    half8 (&Bc)[8], half8 (&Bn)[8],
    float4 (&xw)[2], float4 (&xl)[2],
    f32x16& a00, f32x16& a01, f32x16& a10, f32x16& a11,
    f32x16& c00, f32x16& c01, f32x16& c10, f32x16& c11)
{
    // issue next-next A data and next B frags (stay in flight across BAR)
    if (kc + 2 < 32) {
        xl[0] = *(const float4*)(aptr + (kc + 2) * 32);
        xl[1] = *(const float4*)(aptr + (kc + 2) * 32 + 16);
    }
    if (kc + 1 < 32) {
        #pragma unroll
        for (int f = 0; f < 8; ++f)
            Bn[f] = *(const half8*)(bptr + (size_t)(kc + 1) * 32768 + f * 512);
    }

    // LDS reads of current A fragments
    const char* Ah0 = Acur + a_rd;
    const char* Ah1 = Acur + 4096 + a_rd;
    half8 ah0_0 = *(const half8*)(Ah0);
    half8 ah1_0 = *(const half8*)(Ah0 + 512);
    half8 al0_0 = *(const half8*)(Ah0 + 8192);
    half8 al1_0 = *(const half8*)(Ah0 + 8192 + 512);
    half8 ah0_1 = *(const half8*)(Ah1);
    half8 ah1_1 = *(const half8*)(Ah1 + 512);
    half8 al0_1 = *(const half8*)(Ah1 + 8192);
    half8 al1_1 = *(const half8*)(Ah1 + 8192 + 512);

    // stage next A tile (write-latency hides under MFMA cluster)
    if (kc + 1 < 32) {
        half4 hv, lv;
        cvt_split(xw[0], hv, lv);
        *(half4*)(Anxt + a_off0) = hv; *(half4*)(Anxt + a_off0 + 8192) = lv;
        cvt_split(xw[1], hv, lv);
        *(half4*)(Anxt + a_off1) = hv; *(half4*)(Anxt + a_off1 + 8192) = lv;
    }

    __builtin_amdgcn_s_setprio(1);
    {
        half8 bh0 = Bc[0], bl0 = Bc[1], bh1 = Bc[4], bl1 = Bc[5];
        a00 = MFMA32(ah0_0, bh0, a00); c00 = MFMA32(al0_0, bh0, c00); c00 = MFMA32(ah0_0, bl0, c00);
        a01 = MFMA32(ah0_0, bh1, a01); c01 = MFMA32(al0_0, bh1, c01); c01 = MFMA32(ah0_0, bl1, c01);
        a10 = MFMA32(ah1_0, bh0, a10); c10 = MFMA32(al1_0, bh0, c10); c10 = MFMA32(ah1_0, bl0, c10);
        a11 = MFMA32(ah1_0, bh1, a11); c11 = MFMA32(al1_0, bh1, c11); c11 = MFMA32(ah1_0, bl1, c11);
    }
    {
        half8 bh0 = Bc[2], bl0 = Bc[3], bh1 = Bc[6], bl1 = Bc[7];
        a00 = MFMA32(ah0_1, bh0, a00); c00 = MFMA32(al0_1, bh0, c00); c00 = MFMA32(ah0_1, bl0, c00);
        a01 = MFMA32(ah0_1, bh1, a01); c01 = MFMA32(al0_1, bh1, c01); c01 = MFMA32(ah0_1, bl1, c01);
        a10 = MFMA32(ah1_1, bh0, a10); c10 = MFMA32(al1_1, bh0, c10); c10 = MFMA32(ah1_1, bl0, c10);
        a11 = MFMA32(ah1_1, bh1, a11); c11 = MFMA32(al1_1, bh1, c11); c11 = MFMA32(ah1_1, bl1, c11);
    }
    __builtin_amdgcn_s_setprio(0);

    BAR();
}

__global__ void __launch_bounds__(512, 2)
qir_gemm(const float* __restrict__ xg, const _Float16* __restrict__ wt,
         const float* __restrict__ b1a, const float* __restrict__ w2a, const float* __restrict__ b2a,
         const float* __restrict__ b1p, const float* __restrict__ w2p, const float* __restrict__ b2p,
         float* __restrict__ out)
{
    extern __shared__ char smem[];   // 64KB: A dbuf [0,32K) (reused as H), P [32K,64K)
    const int tid = threadIdx.x;
    const int l  = tid & 63;
    const int w  = tid >> 6;
    const int wm = w >> 2;     // M half (0,1)
    const int wn = w & 3;      // n-slice within block
    // XCD-aligned decode: the 4 blocks sharing an x-panel (2ph x 2nh) have
    // bids m, m+128, m+256, m+384 -> all == m (mod 8) -> same XCD L2.
    const int bid  = blockIdx.x;
    const int mblk = bid & 127;
    const int v    = bid >> 7;
    const int ph   = v & 1;
    const int nh   = v >> 1;
    const int tok0 = mblk * 128;

    const float* __restrict__ b1 = ph ? b1p : b1a;
    const float* __restrict__ w2 = ph ? w2p : w2a;
    const float* __restrict__ b2 = ph ? b2p : b2a;
    const _Float16* __restrict__ wtp = wt + ((size_t)ph << 20);

    char* const Ab0 = smem;
    char* const Ab1 = smem + 16384;

    // A staging: thread -> (row r, k-quads kq and kq+4), swizzled plane offset
    const int r  = tid >> 2;
    const int kq = tid & 3;
    const float* __restrict__ aptr = xg + (size_t)(tok0 + r) * HDIM + kq * 4;
    const int a_off0 = (kq >> 1) * 2048 + aswz(r) + (kq & 1) * 8;
    const int a_off1 = a_off0 + 4096;
    // A frag read: octet (l>>5) plane, row wm*64 + (l&31); +512 = +32 rows
    // (aswz(r+32) == aswz(r)+512 since bit5 not in the XOR mask)
    const int a_rd = (l >> 5) * 2048 + aswz(wm * 64 + (l & 31));

    // B frag pointer (f16 units)
    const _Float16* __restrict__ bptr = wtp + (nh * 4 + wn) * 4096 + (size_t)l * 8;

    f32x16 a00{}, a01{}, a10{}, a11{}, c00{}, c01{}, c10{}, c11{};
    #pragma unroll
    for (int rg = 0; rg < 16; ++rg) {
        a00[rg] = 0.f; a01[rg] = 0.f; a10[rg] = 0.f; a11[rg] = 0.f;
        c00[rg] = 0.f; c01[rg] = 0.f; c10[rg] = 0.f; c11[rg] = 0.f;
    }

    half8 Bc[8], Bn[8];
    float4 xw[2], xl[2];

    // prologue: stage A(0), preload B(0), prefetch x(1)
    {
        float4 v0 = *(const float4*)(aptr);
        float4 v1 = *(const float4*)(aptr + 16);
        half4 hv, lv;
        cvt_split(v0, hv, lv);
        *(half4*)(Ab0 + a_off0) = hv; *(half4*)(Ab0 + a_off0 + 8192) = lv;
        cvt_split(v1, hv, lv);
        *(half4*)(Ab0 + a_off1) = hv; *(half4*)(Ab0 + a_off1 + 8192) = lv;
    }
    #pragma unroll
    for (int f = 0; f < 8; ++f) Bc[f] = *(const half8*)(bptr + f * 512);
    xw[0] = *(const float4*)(aptr + 32);
    xw[1] = *(const float4*)(aptr + 48);
    BAR();

    for (int kk = 0; kk < 16; ++kk) {
        kstep(2 * kk,     aptr, bptr, Ab0, Ab1, a_rd, a_off0, a_off1,
              Bc, Bn, xw, xl, a00, a01, a10, a11, c00, c01, c10, c11);
        kstep(2 * kk + 1, aptr, bptr, Ab1, Ab0, a_rd, a_off0, a_off1,
              Bn, Bc, xl, xw, a00, a01, a10, a11, c00, c01, c10, c11);
    }

    // combine split accumulators + bias + exact gelu (h values kept in acc)
    const int col0 = nh * 256 + wn * 64 + (l & 31);
    const float bb0 = b1[col0], bb1 = b1[col0 + 32];
    #pragma unroll
    for (int rg = 0; rg < 16; ++rg) {
        a00[rg] = gelu_exact(a00[rg] + c00[rg] * LO_SCALE_INV + bb0);
        a01[rg] = gelu_exact(a01[rg] + c01[rg] * LO_SCALE_INV + bb1);
        a10[rg] = gelu_exact(a10[rg] + c10[rg] * LO_SCALE_INV + bb0);
        a11[rg] = gelu_exact(a11[rg] + c11[rg] * LO_SCALE_INV + bb1);
    }

    // ---- fused partial GEMM2 over this block's 256 h-cols ----
    // H plane p gets byte-bit-4 XORed with p (planes are 1KB = 0 mod 128B,
    // otherwise 4-way write conflict across p).
    char* const Hw = smem + w * 4096;            // wave-private [4 planes][32 rows][16B]
    const int hp   = (l >> 3) & 3;               // write plane
    char* const hb = Hw + hp * 1024 + (l & 7) * 2;
    const int hxor = hp << 4;
    const int rp   = l >> 4;                     // read plane
    const int rxor = rp << 4;
    float* const P = (float*)(smem + 32768);     // [8 waves][64 tok][16 e]

    half8 w2h[2], w2l[2];
    #pragma unroll
    for (int nf = 0; nf < 2; ++nf) {
        #pragma unroll
        for (int j = 0; j < 8; ++j) {
            int kg = nh * 256 + wn * 64 + nf * 32 + (l >> 4) * 8 + j;
            float vv = w2[(size_t)kg * NE + (l & 15)];
            _Float16 hh = (_Float16)vv;
            w2h[nf][j] = hh;
            w2l[nf][j] = (_Float16)((vv - (float)hh) * LO_SCALE);
        }
    }

    f32x4 acc2[4], acc2s[4];
    #pragma unroll
    for (int m16 = 0; m16 < 4; ++m16)
        #pragma unroll
        for (int rg = 0; rg < 4; ++rg) { acc2[m16][rg] = 0.f; acc2s[m16][rg] = 0.f; }

#define H2PASS(ACC0, ACC1, NF, PL)                                             \
    {                                                                          \
        _Pragma("unroll")                                                      \
        for (int rg = 0; rg < 16; ++rg) {                                      \
            int row0 = (rg & 3) + 8 * (rg >> 2) + 4 * (l >> 5);                \
            { float vv = ACC0[rg]; _Float16 hh = (_Float16)vv;                 \
              *(_Float16*)(hb + ((row0 * 16) ^ hxor)) =                        \
                  (PL) ? (_Float16)(vv - (float)hh) : hh; }                    \
            { float vv = ACC1[rg]; _Float16 hh = (_Float16)vv;                 \
              *(_Float16*)(hb + (((32 + row0) * 16) ^ hxor)) =                 \
                  (PL) ? (_Float16)(vv - (float)hh) : hh; }                    \
        }                                                                      \
        _Pragma("unroll")                                                      \
        for (int m16 = 0; m16 < 4; ++m16) {                                    \
            half8 a2 = *(const half8*)(Hw + rp * 1024 +                        \
                                       (((m16 * 16 + (l & 15)) * 16) ^ rxor)); \
            acc2[m16] = MFMA16(a2, w2h[NF], acc2[m16]);                        \
            if (!(PL)) acc2s[m16] = MFMA16(a2, w2l[NF], acc2s[m16]);           \
        }                                                                      \
    }

    H2PASS(a00, a10, 0, 0)
    H2PASS(a01, a11, 1, 0)
    H2PASS(a00, a10, 0, 1)
    H2PASS(a01, a11, 1, 1)
#undef H2PASS

    #pragma unroll
    for (int m16 = 0; m16 < 4; ++m16)
        #pragma unroll
        for (int rg = 0; rg < 4; ++rg) {
            int row = m16 * 16 + ((l >> 4) << 2) + rg;
            P[w * 1024 + row * 16 + (l & 15)] =
                acc2[m16][rg] + acc2s[m16][rg] * LO_SCALE_INV;
        }
    __syncthreads();

    #pragma unroll
    for (int rep = 0; rep < 4; ++rep) {
        int oi = tid + rep * 512;
        int t = oi >> 4, e = oi & 15;
        int bw = (t >> 6) * 4, tl = t & 63;
        float sum = 0.5f * b2[e]
                  + P[(bw + 0) * 1024 + tl * 16 + e]
                  + P[(bw + 1) * 1024 + tl * 16 + e]
                  + P[(bw + 2) * 1024 + tl * 16 + e]
                  + P[(bw + 3) * 1024 + tl * 16 + e];
        atomicAdd(out + (ph ? OFF_PH : OFF_PR) + (size_t)(tok0 + t) * NE + e, sum);
    }
}

// ---------------------------------------------------------------------------
// Fallback (R1 kernel, raw-phase variant) if ws too small for the WT image.
// ---------------------------------------------------------------------------
__global__ void __launch_bounds__(512)
qir_mlp(const float* __restrict__ xg,
        const float* __restrict__ w1a, const float* __restrict__ b1a,
        const float* __restrict__ w2a, const float* __restrict__ b2a,
        const float* __restrict__ w1p, const float* __restrict__ b1p,
        const float* __restrict__ w2p, const float* __restrict__ b2p,
        float* __restrict__ out)
{
    __shared__ float sh_w[16][HHALF];
    __shared__ float sh_x[16][68];

    const int tid  = threadIdx.x;
    const int cg   = tid & 63;
    const int tg   = tid >> 6;
    const int tok0 = blockIdx.x * 64;
    const int cA   = cg * 4;
    const int cB   = 256 + cg * 4;

    for (int phase = 0; phase < 2; ++phase) {
        const float* __restrict__ w1 = phase ? w1p : w1a;
        const float* __restrict__ b1 = phase ? b1p : b1a;
        const float* __restrict__ w2 = phase ? w2p : w2a;
        const float* __restrict__ b2 = phase ? b2p : b2a;

        float acc[8][8];
        #pragma unroll
        for (int t = 0; t < 8; ++t)
            #pragma unroll
            for (int c = 0; c < 8; ++c) acc[t][c] = 0.0f;

        float4 wreg[4];
        float4 xreg = make_float4(0.f, 0.f, 0.f, 0.f);

        auto load_chunk = [&](int kc) {
            #pragma unroll
            for (int p = 0; p < 4; ++p) {
                int f  = tid + p * 512;
                int k  = f >> 7;
                int c4 = (f & 127) << 2;
                wreg[p] = *(const float4*)&w1[(kc * 16 + k) * HHALF + c4];
            }
            if (tid < 256) {
                int t  = tid >> 2;
                int k4 = (tid & 3) << 2;
                xreg = *(const float4*)&xg[(size_t)(tok0 + t) * HDIM + kc * 16 + k4];
            }
        };

        load_chunk(0);
        for (int kc = 0; kc < HDIM / 16; ++kc) {
            __syncthreads();
            #pragma unroll
            for (int p = 0; p < 4; ++p) {
                int f  = tid + p * 512;
                int k  = f >> 7;
                int c4 = (f & 127) << 2;
                *(float4*)&sh_w[k][c4] = wreg[p];
            }
            if (tid < 256) {
                int t  = tid >> 2;
                int k4 = (tid & 3) << 2;
                sh_x[k4 + 0][t] = xreg.x;
                sh_x[k4 + 1][t] = xreg.y;
                sh_x[k4 + 2][t] = xreg.z;
                sh_x[k4 + 3][t] = xreg.w;
            }
            __syncthreads();
            if (kc + 1 < HDIM / 16) load_chunk(kc + 1);

            #pragma unroll 4
            for (int k = 0; k < 16; ++k) {
                float4 xa = *(const float4*)&sh_x[k][tg * 8];
                float4 xb = *(const float4*)&sh_x[k][tg * 8 + 4];
                float4 wa = *(const float4*)&sh_w[k][cA];
                float4 wb = *(const float4*)&sh_w[k][cB];
                float xs[8] = {xa.x, xa.y, xa.z, xa.w, xb.x, xb.y, xb.z, xb.w};
                float ws[8] = {wa.x, wa.y, wa.z, wa.w, wb.x, wb.y, wb.z, wb.w};
                #pragma unroll
                for (int t = 0; t < 8; ++t)
                    #pragma unroll
                    for (int c = 0; c < 8; ++c)
                        acc[t][c] = fmaf(xs[t], ws[c], acc[t][c]);
            }
        }

        {
            float4 bA4 = *(const float4*)&b1[cA];
            float4 bB4 = *(const float4*)&b1[cB];
            float bs[8] = {bA4.x, bA4.y, bA4.z, bA4.w, bB4.x, bB4.y, bB4.z, bB4.w};
            #pragma unroll
            for (int t = 0; t < 8; ++t)
                #pragma unroll
                for (int c = 0; c < 8; ++c)
                    acc[t][c] = gelu_exact(acc[t][c] + bs[c]);
        }

        for (int e = 0; e < NE; ++e) {
            float w2v[8];
            #pragma unroll
            for (int j = 0; j < 4; ++j) {
                w2v[j]     = w2[(cA + j) * NE + e];
                w2v[4 + j] = w2[(cB + j) * NE + e];
            }
            float bias2 = b2[e];
            #pragma unroll
            for (int t = 0; t < 8; ++t) {
                float s = 0.0f;
                #pragma unroll
                for (int j = 0; j < 8; ++j) s = fmaf(acc[t][j], w2v[j], s);
                #pragma unroll
                for (int off = 1; off < 64; off <<= 1)
                    s += __shfl_xor(s, off, 64);
                if (cg == 0) {
                    float raw   = s + bias2;
                    int   token = tok0 + tg * 8 + t;
                    out[(phase ? OFF_PH : OFF_PR) + (size_t)token * NE + e] = raw;
                }
            }
        }
    }
}

// ---------------------------------------------------------------------------
// Per-token epilogue: tanh on raw phases; softmax/rotations/probs/top-2.
// ---------------------------------------------------------------------------
__global__ void __launch_bounds__(256)
qir_epilogue(const float* __restrict__ ent, float* __restrict__ out)
{
    __shared__ float sh_c[120], sh_s[120];
    const int tid = threadIdx.x;
    if (tid < 120) {
        int rem = tid, i = 0;
        while (rem >= 15 - i) { rem -= 15 - i; ++i; }
        int j = i + 1 + rem;
        float ang = ent[i * NE + j] * 0.5f;
        sh_c[tid] = cosf(ang);
        sh_s[tid] = sinf(ang);
    }
    __syncthreads();

    const int token = blockIdx.x * 256 + tid;

    #pragma unroll
    for (int q = 0; q < 4; ++q) {
        float4 v = *(const float4*)&out[OFF_PH + (size_t)token * NE + q * 4];
        v.x = tanhf(v.x) * 3.14159265358979323846f;
        v.y = tanhf(v.y) * 3.14159265358979323846f;
        v.z = tanhf(v.z) * 3.14159265358979323846f;
        v.w = tanhf(v.w) * 3.14159265358979323846f;
        *(float4*)&out[OFF_PH + (size_t)token * NE + q * 4] = v;
    }

    float a[16];
    #pragma unroll
    for (int q = 0; q < 4; ++q) {
        float4 v = *(const float4*)&out[OFF_PR + (size_t)token * NE + q * 4];
        a[q*4+0] = v.x; a[q*4+1] = v.y; a[q*4+2] = v.z; a[q*4+3] = v.w;
    }

    float m = fabsf(a[0]);
    #pragma unroll
    for (int e = 1; e < 16; ++e) m = fmaxf(m, fabsf(a[e]));
    float ssum = 0.0f;
    #pragma unroll
    for (int e = 0; e < 16; ++e) { a[e] = expf(fabsf(a[e]) - m); ssum += a[e]; }
    float inv = 1.0f / ssum;
    #pragma unroll
    for (int e = 0; e < 16; ++e) a[e] = sqrtf(a[e] * inv);

    {
        int p = 0;
        #pragma unroll
        for (int i = 0; i < 16; ++i) {
            #pragma unroll
            for (int j = i + 1; j < 16; ++j) {
                float c = sh_c[p], s = sh_s[p]; ++p;
                float ai = a[i], aj = a[j];
                a[i] = c * ai - s * aj;
                a[j] = s * ai + c * aj;
            }
        }
    }

    #pragma unroll
    for (int q = 0; q < 4; ++q)
        *(float4*)&out[OFF_DEC + (size_t)token * NE + q * 4] =
            make_float4(a[q*4], a[q*4+1], a[q*4+2], a[q*4+3]);

    float pr[16];
    float s2 = 0.0f;
    #pragma unroll
    for (int e = 0; e < 16; ++e) { pr[e] = a[e] * a[e]; s2 += pr[e]; }
    float inv2 = 1.0f / fmaxf(s2, 1e-12f);
    #pragma unroll
    for (int e = 0; e < 16; ++e) pr[e] *= inv2;
    #pragma unroll
    for (int q = 0; q < 4; ++q)
        *(float4*)&out[OFF_PR + (size_t)token * NE + q * 4] =
            make_float4(pr[q*4], pr[q*4+1], pr[q*4+2], pr[q*4+3]);

    float bv = pr[0]; int bi = 0;
    #pragma unroll
    for (int e = 1; e < 16; ++e) if (pr[e] > bv) { bv = pr[e]; bi = e; }
    float sv = -1.0f; int si = 0;
    #pragma unroll
    for (int e = 0; e < 16; ++e) if (e != bi && pr[e] > sv) { sv = pr[e]; si = e; }
    float ts = fmaxf(fabsf(bv) + fabsf(sv), 1e-12f);
    out[OFF_TP + (size_t)token * 2 + 0] = bv / ts;
    out[OFF_TP + (size_t)token * 2 + 1] = sv / ts;
    out[OFF_TI + (size_t)token * 2 + 0] = (float)bi;
    out[OFF_TI + (size_t)token * 2 + 1] = (float)si;
}

extern "C" void kernel_launch(void* const* d_in, const int* in_sizes, int n_in,
                              void* d_out, int out_size, void* d_ws, size_t ws_size,
                              hipStream_t stream) {
    const float* xg  = (const float*)d_in[0];
    const float* w1a = (const float*)d_in[1];
    const float* b1a = (const float*)d_in[2];
    const float* w2a = (const float*)d_in[3];
    const float* b2a = (const float*)d_in[4];
    const float* w1p = (const float*)d_in[5];
    const float* b1p = (const float*)d_in[6];
    const float* w2p = (const float*)d_in[7];
    const float* b2p = (const float*)d_in[8];
    const float* ent = (const float*)d_in[9];
    float* out = (float*)d_out;

    if (ws_size >= (size_t)4 * 1024 * 1024) {
        _Float16* wt = (_Float16*)d_ws;
        qir_wtrans<<<1024, 256, 0, stream>>>(w1a, w1p, wt, out);
        qir_gemm<<<512, 512, 65536, stream>>>(xg, wt, b1a, w2a, b2a,
                                              b1p, w2p, b2p, out);
    } else {
        qir_mlp<<<NTOK / 64, 512, 0, stream>>>(xg, w1a, b1a, w2a, b2a,
                                               w1p, b1p, w2p, b2p, out);
    }
    qir_epilogue<<<NTOK / 256, 256, 0, stream>>>(ent, out);
}

// Round 5
// 131.703 us; speedup vs baseline: 1.1737x; 1.1737x over previous
//
#include <hip/hip_runtime.h>
#include <math.h>

#define NTOK   16384
#define HDIM   1024
#define HHALF  512
#define NE     16

// d_out layout (concatenated reference outputs, all f32; indices stored as float)
#define OFF_TP  0
#define OFF_TI  (NTOK * 2)
#define OFF_DEC (NTOK * 4)
#define OFF_PH  (OFF_DEC + NTOK * NE)
#define OFF_PR  (OFF_PH + NTOK * NE)

typedef _Float16 half8 __attribute__((ext_vector_type(8)));
typedef _Float16 half4 __attribute__((ext_vector_type(4)));
typedef float f32x16 __attribute__((ext_vector_type(16)));
typedef float f32x4 __attribute__((ext_vector_type(4)));

#define LO_SCALE     2048.0f
#define LO_SCALE_INV (1.0f / 2048.0f)
#define MFMA32(a,b,c) __builtin_amdgcn_mfma_f32_32x32x16_f16(a,b,c,0,0,0)
#define MFMA16(a,b,c) __builtin_amdgcn_mfma_f32_16x16x32_f16(a,b,c,0,0,0)

// Raw barrier: lgkmcnt(0) gives LDS write-visibility + read completion before
// the barrier; vmcnt is NOT drained, so global prefetches (B kc+1, x kc+2)
// stay in flight across the barrier and are waited with counted vmcnt at
// their consumers (T4). Reads are consumed by MFMAs before this point.
#define BAR() asm volatile("s_waitcnt lgkmcnt(0)\n\ts_barrier" ::: "memory")

__device__ __forceinline__ float gelu_exact(float x) {
    return 0.5f * x * (1.0f + erff(x * 0.70710678118654752440f));
}

__device__ __forceinline__ void cvt_split(float4 v, half4& hi, half4& lo) {
    _Float16 h0 = (_Float16)v.x, h1 = (_Float16)v.y,
             h2 = (_Float16)v.z, h3 = (_Float16)v.w;
    hi = (half4){h0, h1, h2, h3};
    lo = (half4){(_Float16)((v.x - (float)h0) * LO_SCALE),
                 (_Float16)((v.y - (float)h1) * LO_SCALE),
                 (_Float16)((v.z - (float)h2) * LO_SCALE),
                 (_Float16)((v.w - (float)h3) * LO_SCALE)};
}

// ---------------------------------------------------------------------------
// Prologue: build register-fragment B image in ws AND zero the PH/PR raw-sum
// accumulation regions of d_out (gemm blocks atomicAdd into them).
// Image (f16 elems): addr16 = 8*u where u = ((((ph*32+kc)*8+sl)*8+f)*64+l);
// f = nf*4 + kh*2 + pl. Value: col = sl*64+nf*32+(l&31),
// k = kc*32+kh*16+(l>>5)*8+j; pl=0 -> f16(W[k][col]), pl=1 -> (W-hi)*2048.
// ---------------------------------------------------------------------------
__global__ void __launch_bounds__(256)
qir_wtrans(const float* __restrict__ w1a, const float* __restrict__ w1p,
           _Float16* __restrict__ wt, float* __restrict__ out)
{
    int u = blockIdx.x * 256 + threadIdx.x;   // 0..262143
    out[OFF_PH + u] = 0.0f;
    out[OFF_PH + 262144 + u] = 0.0f;

    int l  = u & 63;
    int f  = (u >> 6) & 7;
    int sl = (u >> 9) & 7;
    int kc = (u >> 12) & 31;
    int ph = u >> 17;
    int nf = f >> 2, kh = (f >> 1) & 1, pl = f & 1;
    int col = sl * 64 + nf * 32 + (l & 31);
    int k0  = kc * 32 + kh * 16 + (l >> 5) * 8;
    const float* __restrict__ W = ph ? w1p : w1a;
    half8 v;
    #pragma unroll
    for (int j = 0; j < 8; ++j) {
        float x = W[(size_t)(k0 + j) * HHALF + col];
        _Float16 h = (_Float16)x;
        v[j] = pl ? (_Float16)((x - (float)h) * LO_SCALE) : h;
    }
    *(half8*)&wt[(size_t)u * 8] = v;
}

// ---------------------------------------------------------------------------
// Main GEMM: block = 128 tokens x 256 cols x one phase. B frags loaded
// global->reg (L2-resident, no LDS staging drain); A staged in 2x16KB LDS.
// R3 op order per kstep (prefetch-issue, ds_read+MFMA per kh, stage writes,
// barrier), with the barrier NOT draining vmcnt.
// ---------------------------------------------------------------------------
__device__ __forceinline__ void kstep(
    int kc, const float* __restrict__ aptr, const _Float16* __restrict__ bptr,
    char* Acur, char* Anxt, int a_rd, int a_off0, int a_off1,
    half8 (&Bc)[8], half8 (&Bn)[8],
    float4 (&xw)[2], float4 (&xl)[2],
    f32x16& a00, f32x16& a01, f32x16& a10, f32x16& a11,
    f32x16& c00, f32x16& c01, f32x16& c10, f32x16& c11)
{
    // issue next-next x and next B frags (stay in flight across BAR)
    if (kc + 2 < 32) {
        xl[0] = *(const float4*)(aptr + (kc + 2) * 32);
        xl[1] = *(const float4*)(aptr + (kc + 2) * 32 + 16);
    }
    if (kc + 1 < 32) {
        #pragma unroll
        for (int f = 0; f < 8; ++f)
            Bn[f] = *(const half8*)(bptr + (size_t)(kc + 1) * 32768 + f * 512);
    }
    #pragma unroll
    for (int kh = 0; kh < 2; ++kh) {
        const char* Ah = Acur + kh * 4096 + a_rd;
        half8 ah0 = *(const half8*)(Ah);
        half8 ah1 = *(const half8*)(Ah + 512);
        half8 al0 = *(const half8*)(Ah + 8192);
        half8 al1 = *(const half8*)(Ah + 8192 + 512);
        half8 bh0 = Bc[kh * 2],     bl0 = Bc[kh * 2 + 1];
        half8 bh1 = Bc[4 + kh * 2], bl1 = Bc[4 + kh * 2 + 1];
        a00 = MFMA32(ah0, bh0, a00); c00 = MFMA32(al0, bh0, c00); c00 = MFMA32(ah0, bl0, c00);
        a01 = MFMA32(ah0, bh1, a01); c01 = MFMA32(al0, bh1, c01); c01 = MFMA32(ah0, bl1, c01);
        a10 = MFMA32(ah1, bh0, a10); c10 = MFMA32(al1, bh0, c10); c10 = MFMA32(ah1, bl0, c10);
        a11 = MFMA32(ah1, bh1, a11); c11 = MFMA32(al1, bh1, c11); c11 = MFMA32(ah1, bl1, c11);
    }
    if (kc + 1 < 32) {
        half4 hv, lv;
        cvt_split(xw[0], hv, lv);
        *(half4*)(Anxt + a_off0) = hv; *(half4*)(Anxt + a_off0 + 8192) = lv;
        cvt_split(xw[1], hv, lv);
        *(half4*)(Anxt + a_off1) = hv; *(half4*)(Anxt + a_off1 + 8192) = lv;
    }
    BAR();
}

__global__ void __launch_bounds__(512, 2)
qir_gemm(const float* __restrict__ xg, const _Float16* __restrict__ wt,
         const float* __restrict__ b1a, const float* __restrict__ w2a, const float* __restrict__ b2a,
         const float* __restrict__ b1p, const float* __restrict__ w2p, const float* __restrict__ b2p,
         float* __restrict__ out)
{
    extern __shared__ char smem[];   // 64KB: A dbuf [0,32K) (reused as H), P [32K,64K)
    const int tid = threadIdx.x;
    const int l  = tid & 63;
    const int w  = tid >> 6;
    const int wm = w >> 2;     // M half (0,1)
    const int wn = w & 3;      // n-slice within block
    // XCD-aligned decode: the 4 blocks sharing an x-panel (2ph x 2nh) have
    // bids m, m+128, m+256, m+384 -> all == m (mod 8) -> same XCD L2; each
    // 128-block dispatch phase has a 2MB B working set per XCD.
    const int bid  = blockIdx.x;
    const int mblk = bid & 127;
    const int v    = bid >> 7;
    const int ph   = v & 1;
    const int nh   = v >> 1;
    const int tok0 = mblk * 128;

    const float* __restrict__ b1 = ph ? b1p : b1a;
    const float* __restrict__ w2 = ph ? w2p : w2a;
    const float* __restrict__ b2 = ph ? b2p : b2a;
    const _Float16* __restrict__ wtp = wt + ((size_t)ph << 20);

    char* const Ab0 = smem;
    char* const Ab1 = smem + 16384;

    // A staging: thread -> (row r, k-quads kq and kq+4)
    const int r  = tid >> 2;
    const int kq = tid & 3;
    const float* __restrict__ aptr = xg + (size_t)(tok0 + r) * HDIM + kq * 4;
    const int a_off0 = (kq >> 1) * 2048 + r * 16 + (kq & 1) * 8;
    const int a_off1 = a_off0 + 4096;
    // A frag read: octet (kh*2 + (l>>5)), row wm*64 + mf*32 + (l&31)
    const int a_rd = (l >> 5) * 2048 + (wm * 64 + (l & 31)) * 16;

    // B frag pointer (f16 units)
    const _Float16* __restrict__ bptr = wtp + (nh * 4 + wn) * 4096 + (size_t)l * 8;

    f32x16 a00{}, a01{}, a10{}, a11{}, c00{}, c01{}, c10{}, c11{};
    #pragma unroll
    for (int rg = 0; rg < 16; ++rg) {
        a00[rg] = 0.f; a01[rg] = 0.f; a10[rg] = 0.f; a11[rg] = 0.f;
        c00[rg] = 0.f; c01[rg] = 0.f; c10[rg] = 0.f; c11[rg] = 0.f;
    }

    half8 Bc[8], Bn[8];
    float4 xw[2], xl[2];

    // prologue: stage A(0), preload B(0), prefetch x(1)
    {
        float4 v0 = *(const float4*)(aptr);
        float4 v1 = *(const float4*)(aptr + 16);
        half4 hv, lv;
        cvt_split(v0, hv, lv);
        *(half4*)(Ab0 + a_off0) = hv; *(half4*)(Ab0 + a_off0 + 8192) = lv;
        cvt_split(v1, hv, lv);
        *(half4*)(Ab0 + a_off1) = hv; *(half4*)(Ab0 + a_off1 + 8192) = lv;
    }
    #pragma unroll
    for (int f = 0; f < 8; ++f) Bc[f] = *(const half8*)(bptr + f * 512);
    xw[0] = *(const float4*)(aptr + 32);
    xw[1] = *(const float4*)(aptr + 48);
    BAR();

    for (int kk = 0; kk < 16; ++kk) {
        kstep(2 * kk,     aptr, bptr, Ab0, Ab1, a_rd, a_off0, a_off1,
              Bc, Bn, xw, xl, a00, a01, a10, a11, c00, c01, c10, c11);
        kstep(2 * kk + 1, aptr, bptr, Ab1, Ab0, a_rd, a_off0, a_off1,
              Bn, Bc, xl, xw, a00, a01, a10, a11, c00, c01, c10, c11);
    }

    // combine split accumulators + bias + exact gelu (h values kept in acc)
    const int col0 = nh * 256 + wn * 64 + (l & 31);
    const float bb0 = b1[col0], bb1 = b1[col0 + 32];
    #pragma unroll
    for (int rg = 0; rg < 16; ++rg) {
        a00[rg] = gelu_exact(a00[rg] + c00[rg] * LO_SCALE_INV + bb0);
        a01[rg] = gelu_exact(a01[rg] + c01[rg] * LO_SCALE_INV + bb1);
        a10[rg] = gelu_exact(a10[rg] + c10[rg] * LO_SCALE_INV + bb0);
        a11[rg] = gelu_exact(a11[rg] + c11[rg] * LO_SCALE_INV + bb1);
    }

    // ---- fused partial GEMM2 over this block's 256 h-cols ----
    char* const Hw = smem + w * 4096;            // wave-private [4 oct][64 rows][16B]
    char* const hb = Hw + ((l >> 3) & 3) * 1024 + (l & 7) * 2;
    float* const P = (float*)(smem + 32768);     // [8 waves][64 tok][16 e]

    half8 w2h[2], w2l[2];
    #pragma unroll
    for (int nf = 0; nf < 2; ++nf) {
        #pragma unroll
        for (int j = 0; j < 8; ++j) {
            int kg = nh * 256 + wn * 64 + nf * 32 + (l >> 4) * 8 + j;
            float vv = w2[(size_t)kg * NE + (l & 15)];
            _Float16 hh = (_Float16)vv;
            w2h[nf][j] = hh;
            w2l[nf][j] = (_Float16)((vv - (float)hh) * LO_SCALE);
        }
    }

    f32x4 acc2[4], acc2s[4];
    #pragma unroll
    for (int m16 = 0; m16 < 4; ++m16)
        #pragma unroll
        for (int rg = 0; rg < 4; ++rg) { acc2[m16][rg] = 0.f; acc2s[m16][rg] = 0.f; }

#define H2PASS(ACC0, ACC1, NF, PL)                                             \
    {                                                                          \
        _Pragma("unroll")                                                      \
        for (int rg = 0; rg < 16; ++rg) {                                      \
            int row0 = (rg & 3) + 8 * (rg >> 2) + 4 * (l >> 5);                \
            { float vv = ACC0[rg]; _Float16 hh = (_Float16)vv;                 \
              *(_Float16*)(hb + row0 * 16) =                                   \
                  (PL) ? (_Float16)(vv - (float)hh) : hh; }                    \
            { float vv = ACC1[rg]; _Float16 hh = (_Float16)vv;                 \
              *(_Float16*)(hb + (32 + row0) * 16) =                            \
                  (PL) ? (_Float16)(vv - (float)hh) : hh; }                    \
        }                                                                      \
        _Pragma("unroll")                                                      \
        for (int m16 = 0; m16 < 4; ++m16) {                                    \
            half8 a2 = *(const half8*)(Hw + (l >> 4) * 1024 +                  \
                                       (m16 * 16 + (l & 15)) * 16);            \
            acc2[m16] = MFMA16(a2, w2h[NF], acc2[m16]);                        \
            if (!(PL)) acc2s[m16] = MFMA16(a2, w2l[NF], acc2s[m16]);           \
        }                                                                      \
    }

    H2PASS(a00, a10, 0, 0)
    H2PASS(a01, a11, 1, 0)
    H2PASS(a00, a10, 0, 1)
    H2PASS(a01, a11, 1, 1)
#undef H2PASS

    #pragma unroll
    for (int m16 = 0; m16 < 4; ++m16)
        #pragma unroll
        for (int rg = 0; rg < 4; ++rg) {
            int row = m16 * 16 + ((l >> 4) << 2) + rg;
            P[w * 1024 + row * 16 + (l & 15)] =
                acc2[m16][rg] + acc2s[m16][rg] * LO_SCALE_INV;
        }
    __syncthreads();

    #pragma unroll
    for (int rep = 0; rep < 4; ++rep) {
        int oi = tid + rep * 512;
        int t = oi >> 4, e = oi & 15;
        int bw = (t >> 6) * 4, tl = t & 63;
        float sum = 0.5f * b2[e]
                  + P[(bw + 0) * 1024 + tl * 16 + e]
                  + P[(bw + 1) * 1024 + tl * 16 + e]
                  + P[(bw + 2) * 1024 + tl * 16 + e]
                  + P[(bw + 3) * 1024 + tl * 16 + e];
        atomicAdd(out + (ph ? OFF_PH : OFF_PR) + (size_t)(tok0 + t) * NE + e, sum);
    }
}

// ---------------------------------------------------------------------------
// Fallback (R1 kernel, raw-phase variant) if ws too small for the WT image.
// ---------------------------------------------------------------------------
__global__ void __launch_bounds__(512)
qir_mlp(const float* __restrict__ xg,
        const float* __restrict__ w1a, const float* __restrict__ b1a,
        const float* __restrict__ w2a, const float* __restrict__ b2a,
        const float* __restrict__ w1p, const float* __restrict__ b1p,
        const float* __restrict__ w2p, const float* __restrict__ b2p,
        float* __restrict__ out)
{
    __shared__ float sh_w[16][HHALF];
    __shared__ float sh_x[16][68];

    const int tid  = threadIdx.x;
    const int cg   = tid & 63;
    const int tg   = tid >> 6;
    const int tok0 = blockIdx.x * 64;
    const int cA   = cg * 4;
    const int cB   = 256 + cg * 4;

    for (int phase = 0; phase < 2; ++phase) {
        const float* __restrict__ w1 = phase ? w1p : w1a;
        const float* __restrict__ b1 = phase ? b1p : b1a;
        const float* __restrict__ w2 = phase ? w2p : w2a;
        const float* __restrict__ b2 = phase ? b2p : b2a;

        float acc[8][8];
        #pragma unroll
        for (int t = 0; t < 8; ++t)
            #pragma unroll
            for (int c = 0; c < 8; ++c) acc[t][c] = 0.0f;

        float4 wreg[4];
        float4 xreg = make_float4(0.f, 0.f, 0.f, 0.f);

        auto load_chunk = [&](int kc) {
            #pragma unroll
            for (int p = 0; p < 4; ++p) {
                int f  = tid + p * 512;
                int k  = f >> 7;
                int c4 = (f & 127) << 2;
                wreg[p] = *(const float4*)&w1[(kc * 16 + k) * HHALF + c4];
            }
            if (tid < 256) {
                int t  = tid >> 2;
                int k4 = (tid & 3) << 2;
                xreg = *(const float4*)&xg[(size_t)(tok0 + t) * HDIM + kc * 16 + k4];
            }
        };

        load_chunk(0);
        for (int kc = 0; kc < HDIM / 16; ++kc) {
            __syncthreads();
            #pragma unroll
            for (int p = 0; p < 4; ++p) {
                int f  = tid + p * 512;
                int k  = f >> 7;
                int c4 = (f & 127) << 2;
                *(float4*)&sh_w[k][c4] = wreg[p];
            }
            if (tid < 256) {
                int t  = tid >> 2;
                int k4 = (tid & 3) << 2;
                sh_x[k4 + 0][t] = xreg.x;
                sh_x[k4 + 1][t] = xreg.y;
                sh_x[k4 + 2][t] = xreg.z;
                sh_x[k4 + 3][t] = xreg.w;
            }
            __syncthreads();
            if (kc + 1 < HDIM / 16) load_chunk(kc + 1);

            #pragma unroll 4
            for (int k = 0; k < 16; ++k) {
                float4 xa = *(const float4*)&sh_x[k][tg * 8];
                float4 xb = *(const float4*)&sh_x[k][tg * 8 + 4];
                float4 wa = *(const float4*)&sh_w[k][cA];
                float4 wb = *(const float4*)&sh_w[k][cB];
                float xs[8] = {xa.x, xa.y, xa.z, xa.w, xb.x, xb.y, xb.z, xb.w};
                float ws[8] = {wa.x, wa.y, wa.z, wa.w, wb.x, wb.y, wb.z, wb.w};
                #pragma unroll
                for (int t = 0; t < 8; ++t)
                    #pragma unroll
                    for (int c = 0; c < 8; ++c)
                        acc[t][c] = fmaf(xs[t], ws[c], acc[t][c]);
            }
        }

        {
            float4 bA4 = *(const float4*)&b1[cA];
            float4 bB4 = *(const float4*)&b1[cB];
            float bs[8] = {bA4.x, bA4.y, bA4.z, bA4.w, bB4.x, bB4.y, bB4.z, bB4.w};
            #pragma unroll
            for (int t = 0; t < 8; ++t)
                #pragma unroll
                for (int c = 0; c < 8; ++c)
                    acc[t][c] = gelu_exact(acc[t][c] + bs[c]);
        }

        for (int e = 0; e < NE; ++e) {
            float w2v[8];
            #pragma unroll
            for (int j = 0; j < 4; ++j) {
                w2v[j]     = w2[(cA + j) * NE + e];
                w2v[4 + j] = w2[(cB + j) * NE + e];
            }
            float bias2 = b2[e];
            #pragma unroll
            for (int t = 0; t < 8; ++t) {
                float s = 0.0f;
                #pragma unroll
                for (int j = 0; j < 8; ++j) s = fmaf(acc[t][j], w2v[j], s);
                #pragma unroll
                for (int off = 1; off < 64; off <<= 1)
                    s += __shfl_xor(s, off, 64);
                if (cg == 0) {
                    float raw   = s + bias2;
                    int   token = tok0 + tg * 8 + t;
                    out[(phase ? OFF_PH : OFF_PR) + (size_t)token * NE + e] = raw;
                }
            }
        }
    }
}

// ---------------------------------------------------------------------------
// Per-token epilogue: tanh on raw phases; softmax/rotations/probs/top-2.
// ---------------------------------------------------------------------------
__global__ void __launch_bounds__(256)
qir_epilogue(const float* __restrict__ ent, float* __restrict__ out)
{
    __shared__ float sh_c[120], sh_s[120];
    const int tid = threadIdx.x;
    if (tid < 120) {
        int rem = tid, i = 0;
        while (rem >= 15 - i) { rem -= 15 - i; ++i; }
        int j = i + 1 + rem;
        float ang = ent[i * NE + j] * 0.5f;
        sh_c[tid] = cosf(ang);
        sh_s[tid] = sinf(ang);
    }
    __syncthreads();

    const int token = blockIdx.x * 256 + tid;

    #pragma unroll
    for (int q = 0; q < 4; ++q) {
        float4 v = *(const float4*)&out[OFF_PH + (size_t)token * NE + q * 4];
        v.x = tanhf(v.x) * 3.14159265358979323846f;
        v.y = tanhf(v.y) * 3.14159265358979323846f;
        v.z = tanhf(v.z) * 3.14159265358979323846f;
        v.w = tanhf(v.w) * 3.14159265358979323846f;
        *(float4*)&out[OFF_PH + (size_t)token * NE + q * 4] = v;
    }

    float a[16];
    #pragma unroll
    for (int q = 0; q < 4; ++q) {
        float4 v = *(const float4*)&out[OFF_PR + (size_t)token * NE + q * 4];
        a[q*4+0] = v.x; a[q*4+1] = v.y; a[q*4+2] = v.z; a[q*4+3] = v.w;
    }

    float m = fabsf(a[0]);
    #pragma unroll
    for (int e = 1; e < 16; ++e) m = fmaxf(m, fabsf(a[e]));
    float ssum = 0.0f;
    #pragma unroll
    for (int e = 0; e < 16; ++e) { a[e] = expf(fabsf(a[e]) - m); ssum += a[e]; }
    float inv = 1.0f / ssum;
    #pragma unroll
    for (int e = 0; e < 16; ++e) a[e] = sqrtf(a[e] * inv);

    {
        int p = 0;
        #pragma unroll
        for (int i = 0; i < 16; ++i) {
            #pragma unroll
            for (int j = i + 1; j < 16; ++j) {
                float c = sh_c[p], s = sh_s[p]; ++p;
                float ai = a[i], aj = a[j];
                a[i] = c * ai - s * aj;
                a[j] = s * ai + c * aj;
            }
        }
    }

    #pragma unroll
    for (int q = 0; q < 4; ++q)
        *(float4*)&out[OFF_DEC + (size_t)token * NE + q * 4] =
            make_float4(a[q*4], a[q*4+1], a[q*4+2], a[q*4+3]);

    float pr[16];
    float s2 = 0.0f;
    #pragma unroll
    for (int e = 0; e < 16; ++e) { pr[e] = a[e] * a[e]; s2 += pr[e]; }
    float inv2 = 1.0f / fmaxf(s2, 1e-12f);
    #pragma unroll
    for (int e = 0; e < 16; ++e) pr[e] *= inv2;
    #pragma unroll
    for (int q = 0; q < 4; ++q)
        *(float4*)&out[OFF_PR + (size_t)token * NE + q * 4] =
            make_float4(pr[q*4], pr[q*4+1], pr[q*4+2], pr[q*4+3]);

    float bv = pr[0]; int bi = 0;
    #pragma unroll
    for (int e = 1; e < 16; ++e) if (pr[e] > bv) { bv = pr[e]; bi = e; }
    float sv = -1.0f; int si = 0;
    #pragma unroll
    for (int e = 0; e < 16; ++e) if (e != bi && pr[e] > sv) { sv = pr[e]; si = e; }
    float ts = fmaxf(fabsf(bv) + fabsf(sv), 1e-12f);
    out[OFF_TP + (size_t)token * 2 + 0] = bv / ts;
    out[OFF_TP + (size_t)token * 2 + 1] = sv / ts;
    out[OFF_TI + (size_t)token * 2 + 0] = (float)bi;
    out[OFF_TI + (size_t)token * 2 + 1] = (float)si;
}

extern "C" void kernel_launch(void* const* d_in, const int* in_sizes, int n_in,
                              void* d_out, int out_size, void* d_ws, size_t ws_size,
                              hipStream_t stream) {
    const float* xg  = (const float*)d_in[0];
    const float* w1a = (const float*)d_in[1];
    const float* b1a = (const float*)d_in[2];
    const float* w2a = (const float*)d_in[3];
    const float* b2a = (const float*)d_in[4];
    const float* w1p = (const float*)d_in[5];
    const float* b1p = (const float*)d_in[6];
    const float* w2p = (const float*)d_in[7];
    const float* b2p = (const float*)d_in[8];
    const float* ent = (const float*)d_in[9];
    float* out = (float*)d_out;

    if (ws_size >= (size_t)4 * 1024 * 1024) {
        _Float16* wt = (_Float16*)d_ws;
        qir_wtrans<<<1024, 256, 0, stream>>>(w1a, w1p, wt, out);
        qir_gemm<<<512, 512, 65536, stream>>>(xg, wt, b1a, w2a, b2a,
                                              b1p, w2p, b2p, out);
    } else {
        qir_mlp<<<NTOK / 64, 512, 0, stream>>>(xg, w1a, b1a, w2a, b2a,
                                               w1p, b1p, w2p, b2p, out);
    }
    qir_epilogue<<<NTOK / 256, 256, 0, stream>>>(ent, out);
}

// Round 6
// 120.766 us; speedup vs baseline: 1.2800x; 1.0906x over previous
//
#include <hip/hip_runtime.h>
#include <math.h>

#define NTOK   16384
#define HDIM   1024
#define HHALF  512
#define NE     16

// d_out layout (concatenated reference outputs, all f32; indices stored as float)
#define OFF_TP  0
#define OFF_TI  (NTOK * 2)
#define OFF_DEC (NTOK * 4)
#define OFF_PH  (OFF_DEC + NTOK * NE)
#define OFF_PR  (OFF_PH + NTOK * NE)

typedef _Float16 half8 __attribute__((ext_vector_type(8)));
typedef _Float16 half4 __attribute__((ext_vector_type(4)));
typedef float f32x16 __attribute__((ext_vector_type(16)));
typedef float f32x4 __attribute__((ext_vector_type(4)));

#define LO_SCALE     2048.0f
#define LO_SCALE_INV (1.0f / 2048.0f)
#define MFMA32(a,b,c) __builtin_amdgcn_mfma_f32_32x32x16_f16(a,b,c,0,0,0)
#define MFMA16(a,b,c) __builtin_amdgcn_mfma_f32_16x16x32_f16(a,b,c,0,0,0)

// Raw barrier: lgkmcnt(0) gives LDS write-visibility + read completion before
// the barrier; vmcnt is NOT drained (global prefetches stay in flight).
#define BAR() asm volatile("s_waitcnt lgkmcnt(0)\n\ts_barrier" ::: "memory")

__device__ __forceinline__ float gelu_exact(float x) {
    return 0.5f * x * (1.0f + erff(x * 0.70710678118654752440f));
}

__device__ __forceinline__ void cvt_split(float4 v, half4& hi, half4& lo) {
    _Float16 h0 = (_Float16)v.x, h1 = (_Float16)v.y,
             h2 = (_Float16)v.z, h3 = (_Float16)v.w;
    hi = (half4){h0, h1, h2, h3};
    lo = (half4){(_Float16)((v.x - (float)h0) * LO_SCALE),
                 (_Float16)((v.y - (float)h1) * LO_SCALE),
                 (_Float16)((v.z - (float)h2) * LO_SCALE),
                 (_Float16)((v.w - (float)h3) * LO_SCALE)};
}

// ---------------------------------------------------------------------------
// Prologue: build register-fragment B image in ws AND zero the PH/PR raw-sum
// accumulation regions of d_out (gemm blocks atomicAdd into them).
// Image (f16 elems): addr16 = 8*u where u = ((((ph*32+kc)*8+sl)*8+f)*64+l);
// f = nf*4 + kh*2 + pl. Value: col = sl*64+nf*32+(l&31),
// k = kc*32+kh*16+(l>>5)*8+j; pl=0 -> f16(W[k][col]), pl=1 -> (W-hi)*2048.
// ---------------------------------------------------------------------------
__global__ void __launch_bounds__(256)
qir_wtrans(const float* __restrict__ w1a, const float* __restrict__ w1p,
           _Float16* __restrict__ wt, float* __restrict__ out)
{
    int u = blockIdx.x * 256 + threadIdx.x;   // 0..262143
    out[OFF_PH + u] = 0.0f;
    out[OFF_PH + 262144 + u] = 0.0f;

    int l  = u & 63;
    int f  = (u >> 6) & 7;
    int sl = (u >> 9) & 7;
    int kc = (u >> 12) & 31;
    int ph = u >> 17;
    int nf = f >> 2, kh = (f >> 1) & 1, pl = f & 1;
    int col = sl * 64 + nf * 32 + (l & 31);
    int k0  = kc * 32 + kh * 16 + (l >> 5) * 8;
    const float* __restrict__ W = ph ? w1p : w1a;
    half8 v;
    #pragma unroll
    for (int j = 0; j < 8; ++j) {
        float x = W[(size_t)(k0 + j) * HHALF + col];
        _Float16 h = (_Float16)x;
        v[j] = pl ? (_Float16)((x - (float)h) * LO_SCALE) : h;
    }
    *(half8*)&wt[(size_t)u * 8] = v;
}

// ---------------------------------------------------------------------------
// Main GEMM: block = 128 tokens x 256 cols x one phase. Wave tile 128x32:
// each of the 8 waves owns a DISTINCT 32-col slice -> no duplicate B loads
// (4 B-frag loads/wave/kstep, half of R5's traffic). A staged in 2x16KB LDS.
// ---------------------------------------------------------------------------
__device__ __forceinline__ void kstep(
    int kc, const float* __restrict__ aptr, const _Float16* __restrict__ bptr,
    char* Acur, char* Anxt, int a_rd, int a_off0, int a_off1,
    half8 (&Bc)[4], half8 (&Bn)[4],
    float4 (&xw)[2], float4 (&xl)[2],
    f32x16 (&am)[4], f32x16 (&cm)[4])
{
    // issue next-next x and next B frags (stay in flight across BAR)
    if (kc + 2 < 32) {
        xl[0] = *(const float4*)(aptr + (kc + 2) * 32);
        xl[1] = *(const float4*)(aptr + (kc + 2) * 32 + 16);
    }
    if (kc + 1 < 32) {
        #pragma unroll
        for (int j = 0; j < 4; ++j)
            Bn[j] = *(const half8*)(bptr + (size_t)(kc + 1) * 32768 + j * 512);
    }
    #pragma unroll
    for (int kh = 0; kh < 2; ++kh) {
        const char* Ah = Acur + kh * 4096 + a_rd;
        half8 ah[4], al[4];
        #pragma unroll
        for (int mf = 0; mf < 4; ++mf) {
            ah[mf] = *(const half8*)(Ah + mf * 512);
            al[mf] = *(const half8*)(Ah + 8192 + mf * 512);
        }
        half8 bh = Bc[kh * 2], bl = Bc[kh * 2 + 1];
        #pragma unroll
        for (int mf = 0; mf < 4; ++mf) {
            am[mf] = MFMA32(ah[mf], bh, am[mf]);
            cm[mf] = MFMA32(al[mf], bh, cm[mf]);
            cm[mf] = MFMA32(ah[mf], bl, cm[mf]);
        }
    }
    if (kc + 1 < 32) {
        half4 hv, lv;
        cvt_split(xw[0], hv, lv);
        *(half4*)(Anxt + a_off0) = hv; *(half4*)(Anxt + a_off0 + 8192) = lv;
        cvt_split(xw[1], hv, lv);
        *(half4*)(Anxt + a_off1) = hv; *(half4*)(Anxt + a_off1 + 8192) = lv;
    }
    BAR();
}

__global__ void __launch_bounds__(512, 2)
qir_gemm(const float* __restrict__ xg, const _Float16* __restrict__ wt,
         const float* __restrict__ b1a, const float* __restrict__ w2a, const float* __restrict__ b2a,
         const float* __restrict__ b1p, const float* __restrict__ w2p, const float* __restrict__ b2p,
         float* __restrict__ out)
{
    extern __shared__ char smem[];   // 64KB. K-loop: A dbuf [0,32K). Epilogue:
                                     // H [0,40960) (stride-80 rows), then P [0,64K).
    const int tid = threadIdx.x;
    const int l  = tid & 63;
    const int w  = tid >> 6;   // wave 0..7 owns col slice w*32..w*32+31
    // XCD-aligned decode: the 4 blocks sharing an x-panel (2ph x 2nh) have
    // bids m, m+128, m+256, m+384 -> all == m (mod 8) -> same XCD L2.
    const int bid  = blockIdx.x;
    const int mblk = bid & 127;
    const int v    = bid >> 7;
    const int ph   = v & 1;
    const int nh   = v >> 1;
    const int tok0 = mblk * 128;

    const float* __restrict__ b1 = ph ? b1p : b1a;
    const float* __restrict__ w2 = ph ? w2p : w2a;
    const float* __restrict__ b2 = ph ? b2p : b2a;
    const _Float16* __restrict__ wtp = wt + ((size_t)ph << 20);

    char* const Ab0 = smem;
    char* const Ab1 = smem + 16384;

    // A staging: thread -> (row r, k-quads kq and kq+4)
    const int r  = tid >> 2;
    const int kq = tid & 3;
    const float* __restrict__ aptr = xg + (size_t)(tok0 + r) * HDIM + kq * 4;
    const int a_off0 = (kq >> 1) * 2048 + r * 16 + (kq & 1) * 8;
    const int a_off1 = a_off0 + 4096;
    // A frag read: k-plane (l>>5), rows mf*32 + (l&31)
    const int a_rd = (l >> 5) * 2048 + (l & 31) * 16;

    // B frag pointer (f16 units): col32 index c32 = nh*8 + w -> sl=c32>>1, nf=c32&1
    const int c32 = nh * 8 + w;
    const _Float16* __restrict__ bptr =
        wtp + (c32 >> 1) * 4096 + (c32 & 1) * 2048 + (size_t)l * 8;

    f32x16 am[4], cm[4];
    #pragma unroll
    for (int mf = 0; mf < 4; ++mf)
        #pragma unroll
        for (int rg = 0; rg < 16; ++rg) { am[mf][rg] = 0.f; cm[mf][rg] = 0.f; }

    half8 Bc[4], Bn[4];
    float4 xw[2], xl[2];

    // prologue: stage A(0), preload B(0), prefetch x(1)
    {
        float4 v0 = *(const float4*)(aptr);
        float4 v1 = *(const float4*)(aptr + 16);
        half4 hv, lv;
        cvt_split(v0, hv, lv);
        *(half4*)(Ab0 + a_off0) = hv; *(half4*)(Ab0 + a_off0 + 8192) = lv;
        cvt_split(v1, hv, lv);
        *(half4*)(Ab0 + a_off1) = hv; *(half4*)(Ab0 + a_off1 + 8192) = lv;
    }
    #pragma unroll
    for (int j = 0; j < 4; ++j) Bc[j] = *(const half8*)(bptr + j * 512);
    xw[0] = *(const float4*)(aptr + 32);
    xw[1] = *(const float4*)(aptr + 48);
    BAR();

    for (int kk = 0; kk < 16; ++kk) {
        kstep(2 * kk,     aptr, bptr, Ab0, Ab1, a_rd, a_off0, a_off1,
              Bc, Bn, xw, xl, am, cm);
        kstep(2 * kk + 1, aptr, bptr, Ab1, Ab0, a_rd, a_off0, a_off1,
              Bn, Bc, xl, xw, am, cm);
    }

    // combine split accumulators + bias + exact gelu (all rows share one col)
    const float bb = b1[nh * 256 + w * 32 + (l & 31)];
    #pragma unroll
    for (int mf = 0; mf < 4; ++mf)
        #pragma unroll
        for (int rg = 0; rg < 16; ++rg)
            am[mf][rg] = gelu_exact(am[mf][rg] + cm[mf][rg] * LO_SCALE_INV + bb);

    // ---- fused partial GEMM2: each wave contracts its 32 h-cols (K=32) ----
    // H: wave-private [64 rows][stride 80B] f16 tile (pad kills bank conflicts)
    char* const Hw = smem + w * 5120;

    half8 w2h, w2l;
    #pragma unroll
    for (int j = 0; j < 8; ++j) {
        int kg = nh * 256 + w * 32 + (l >> 4) * 8 + j;
        float vv = w2[(size_t)kg * NE + (l & 15)];
        _Float16 hh = (_Float16)vv;
        w2h[j] = hh;
        w2l[j] = (_Float16)((vv - (float)hh) * LO_SCALE);
    }

    f32x4 acc2[2][4], acc2s[2][4];
    #pragma unroll
    for (int p2 = 0; p2 < 2; ++p2)
        #pragma unroll
        for (int m16 = 0; m16 < 4; ++m16)
            #pragma unroll
            for (int rg = 0; rg < 4; ++rg) { acc2[p2][m16][rg] = 0.f; acc2s[p2][m16][rg] = 0.f; }

    #pragma unroll
    for (int p2 = 0; p2 < 2; ++p2) {
        // hi pass: stage h_hi for rows p2*64..p2*64+63, MFMA vs w2h and w2l
        #pragma unroll
        for (int fr = 0; fr < 2; ++fr)
            #pragma unroll
            for (int rg = 0; rg < 16; ++rg) {
                int row = fr * 32 + (rg & 3) + 8 * (rg >> 2) + 4 * (l >> 5);
                float vv = am[p2 * 2 + fr][rg];
                *(_Float16*)(Hw + row * 80 + (l & 31) * 2) = (_Float16)vv;
            }
        #pragma unroll
        for (int m16 = 0; m16 < 4; ++m16) {
            half8 a2 = *(const half8*)(Hw + (m16 * 16 + (l & 15)) * 80 + (l >> 4) * 16);
            acc2[p2][m16]  = MFMA16(a2, w2h, acc2[p2][m16]);
            acc2s[p2][m16] = MFMA16(a2, w2l, acc2s[p2][m16]);
        }
        // lo pass: stage h residual (unscaled), MFMA vs w2h only
        #pragma unroll
        for (int fr = 0; fr < 2; ++fr)
            #pragma unroll
            for (int rg = 0; rg < 16; ++rg) {
                int row = fr * 32 + (rg & 3) + 8 * (rg >> 2) + 4 * (l >> 5);
                float vv = am[p2 * 2 + fr][rg];
                _Float16 hh = (_Float16)vv;
                *(_Float16*)(Hw + row * 80 + (l & 31) * 2) = (_Float16)(vv - (float)hh);
            }
        #pragma unroll
        for (int m16 = 0; m16 < 4; ++m16) {
            half8 a2 = *(const half8*)(Hw + (m16 * 16 + (l & 15)) * 80 + (l >> 4) * 16);
            acc2[p2][m16] = MFMA16(a2, w2h, acc2[p2][m16]);
        }
    }

    // ---- cross-wave reduction: P overlays the whole 64KB after a sync ----
    __syncthreads();
    float* const P = (float*)smem;   // [8 waves][128 tok][16 e] f32 = 64KB
    #pragma unroll
    for (int p2 = 0; p2 < 2; ++p2)
        #pragma unroll
        for (int m16 = 0; m16 < 4; ++m16)
            #pragma unroll
            for (int rg = 0; rg < 4; ++rg) {
                int t = p2 * 64 + m16 * 16 + ((l >> 4) << 2) + rg;
                P[w * 2048 + t * 16 + (l & 15)] =
                    acc2[p2][m16][rg] + acc2s[p2][m16][rg] * LO_SCALE_INV;
            }
    __syncthreads();

    #pragma unroll
    for (int rep = 0; rep < 4; ++rep) {
        int oi = tid + rep * 512;
        int t = oi >> 4, e = oi & 15;
        float sum = 0.5f * b2[e];
        #pragma unroll
        for (int w8 = 0; w8 < 8; ++w8) sum += P[w8 * 2048 + t * 16 + e];
        atomicAdd(out + (ph ? OFF_PH : OFF_PR) + (size_t)(tok0 + t) * NE + e, sum);
    }
}

// ---------------------------------------------------------------------------
// Fallback (R1 kernel, raw-phase variant) if ws too small for the WT image.
// ---------------------------------------------------------------------------
__global__ void __launch_bounds__(512)
qir_mlp(const float* __restrict__ xg,
        const float* __restrict__ w1a, const float* __restrict__ b1a,
        const float* __restrict__ w2a, const float* __restrict__ b2a,
        const float* __restrict__ w1p, const float* __restrict__ b1p,
        const float* __restrict__ w2p, const float* __restrict__ b2p,
        float* __restrict__ out)
{
    __shared__ float sh_w[16][HHALF];
    __shared__ float sh_x[16][68];

    const int tid  = threadIdx.x;
    const int cg   = tid & 63;
    const int tg   = tid >> 6;
    const int tok0 = blockIdx.x * 64;
    const int cA   = cg * 4;
    const int cB   = 256 + cg * 4;

    for (int phase = 0; phase < 2; ++phase) {
        const float* __restrict__ w1 = phase ? w1p : w1a;
        const float* __restrict__ b1 = phase ? b1p : b1a;
        const float* __restrict__ w2 = phase ? w2p : w2a;
        const float* __restrict__ b2 = phase ? b2p : b2a;

        float acc[8][8];
        #pragma unroll
        for (int t = 0; t < 8; ++t)
            #pragma unroll
            for (int c = 0; c < 8; ++c) acc[t][c] = 0.0f;

        float4 wreg[4];
        float4 xreg = make_float4(0.f, 0.f, 0.f, 0.f);

        auto load_chunk = [&](int kc) {
            #pragma unroll
            for (int p = 0; p < 4; ++p) {
                int f  = tid + p * 512;
                int k  = f >> 7;
                int c4 = (f & 127) << 2;
                wreg[p] = *(const float4*)&w1[(kc * 16 + k) * HHALF + c4];
            }
            if (tid < 256) {
                int t  = tid >> 2;
                int k4 = (tid & 3) << 2;
                xreg = *(const float4*)&xg[(size_t)(tok0 + t) * HDIM + kc * 16 + k4];
            }
        };

        load_chunk(0);
        for (int kc = 0; kc < HDIM / 16; ++kc) {
            __syncthreads();
            #pragma unroll
            for (int p = 0; p < 4; ++p) {
                int f  = tid + p * 512;
                int k  = f >> 7;
                int c4 = (f & 127) << 2;
                *(float4*)&sh_w[k][c4] = wreg[p];
            }
            if (tid < 256) {
                int t  = tid >> 2;
                int k4 = (tid & 3) << 2;
                sh_x[k4 + 0][t] = xreg.x;
                sh_x[k4 + 1][t] = xreg.y;
                sh_x[k4 + 2][t] = xreg.z;
                sh_x[k4 + 3][t] = xreg.w;
            }
            __syncthreads();
            if (kc + 1 < HDIM / 16) load_chunk(kc + 1);

            #pragma unroll 4
            for (int k = 0; k < 16; ++k) {
                float4 xa = *(const float4*)&sh_x[k][tg * 8];
                float4 xb = *(const float4*)&sh_x[k][tg * 8 + 4];
                float4 wa = *(const float4*)&sh_w[k][cA];
                float4 wb = *(const float4*)&sh_w[k][cB];
                float xs[8] = {xa.x, xa.y, xa.z, xa.w, xb.x, xb.y, xb.z, xb.w};
                float ws[8] = {wa.x, wa.y, wa.z, wa.w, wb.x, wb.y, wb.z, wb.w};
                #pragma unroll
                for (int t = 0; t < 8; ++t)
                    #pragma unroll
                    for (int c = 0; c < 8; ++c)
                        acc[t][c] = fmaf(xs[t], ws[c], acc[t][c]);
            }
        }

        {
            float4 bA4 = *(const float4*)&b1[cA];
            float4 bB4 = *(const float4*)&b1[cB];
            float bs[8] = {bA4.x, bA4.y, bA4.z, bA4.w, bB4.x, bB4.y, bB4.z, bB4.w};
            #pragma unroll
            for (int t = 0; t < 8; ++t)
                #pragma unroll
                for (int c = 0; c < 8; ++c)
                    acc[t][c] = gelu_exact(acc[t][c] + bs[c]);
        }

        for (int e = 0; e < NE; ++e) {
            float w2v[8];
            #pragma unroll
            for (int j = 0; j < 4; ++j) {
                w2v[j]     = w2[(cA + j) * NE + e];
                w2v[4 + j] = w2[(cB + j) * NE + e];
            }
            float bias2 = b2[e];
            #pragma unroll
            for (int t = 0; t < 8; ++t) {
                float s = 0.0f;
                #pragma unroll
                for (int j = 0; j < 8; ++j) s = fmaf(acc[t][j], w2v[j], s);
                #pragma unroll
                for (int off = 1; off < 64; off <<= 1)
                    s += __shfl_xor(s, off, 64);
                if (cg == 0) {
                    float raw   = s + bias2;
                    int   token = tok0 + tg * 8 + t;
                    out[(phase ? OFF_PH : OFF_PR) + (size_t)token * NE + e] = raw;
                }
            }
        }
    }
}

// ---------------------------------------------------------------------------
// Per-token epilogue: tanh on raw phases; softmax/rotations/probs/top-2.
// ---------------------------------------------------------------------------
__global__ void __launch_bounds__(256)
qir_epilogue(const float* __restrict__ ent, float* __restrict__ out)
{
    __shared__ float sh_c[120], sh_s[120];
    const int tid = threadIdx.x;
    if (tid < 120) {
        int rem = tid, i = 0;
        while (rem >= 15 - i) { rem -= 15 - i; ++i; }
        int j = i + 1 + rem;
        float ang = ent[i * NE + j] * 0.5f;
        sh_c[tid] = cosf(ang);
        sh_s[tid] = sinf(ang);
    }
    __syncthreads();

    const int token = blockIdx.x * 256 + tid;

    #pragma unroll
    for (int q = 0; q < 4; ++q) {
        float4 v = *(const float4*)&out[OFF_PH + (size_t)token * NE + q * 4];
        v.x = tanhf(v.x) * 3.14159265358979323846f;
        v.y = tanhf(v.y) * 3.14159265358979323846f;
        v.z = tanhf(v.z) * 3.14159265358979323846f;
        v.w = tanhf(v.w) * 3.14159265358979323846f;
        *(float4*)&out[OFF_PH + (size_t)token * NE + q * 4] = v;
    }

    float a[16];
    #pragma unroll
    for (int q = 0; q < 4; ++q) {
        float4 v = *(const float4*)&out[OFF_PR + (size_t)token * NE + q * 4];
        a[q*4+0] = v.x; a[q*4+1] = v.y; a[q*4+2] = v.z; a[q*4+3] = v.w;
    }

    float m = fabsf(a[0]);
    #pragma unroll
    for (int e = 1; e < 16; ++e) m = fmaxf(m, fabsf(a[e]));
    float ssum = 0.0f;
    #pragma unroll
    for (int e = 0; e < 16; ++e) { a[e] = expf(fabsf(a[e]) - m); ssum += a[e]; }
    float inv = 1.0f / ssum;
    #pragma unroll
    for (int e = 0; e < 16; ++e) a[e] = sqrtf(a[e] * inv);

    {
        int p = 0;
        #pragma unroll
        for (int i = 0; i < 16; ++i) {
            #pragma unroll
            for (int j = i + 1; j < 16; ++j) {
                float c = sh_c[p], s = sh_s[p]; ++p;
                float ai = a[i], aj = a[j];
                a[i] = c * ai - s * aj;
                a[j] = s * ai + c * aj;
            }
        }
    }

    #pragma unroll
    for (int q = 0; q < 4; ++q)
        *(float4*)&out[OFF_DEC + (size_t)token * NE + q * 4] =
            make_float4(a[q*4], a[q*4+1], a[q*4+2], a[q*4+3]);

    float pr[16];
    float s2 = 0.0f;
    #pragma unroll
    for (int e = 0; e < 16; ++e) { pr[e] = a[e] * a[e]; s2 += pr[e]; }
    float inv2 = 1.0f / fmaxf(s2, 1e-12f);
    #pragma unroll
    for (int e = 0; e < 16; ++e) pr[e] *= inv2;
    #pragma unroll
    for (int q = 0; q < 4; ++q)
        *(float4*)&out[OFF_PR + (size_t)token * NE + q * 4] =
            make_float4(pr[q*4], pr[q*4+1], pr[q*4+2], pr[q*4+3]);

    float bv = pr[0]; int bi = 0;
    #pragma unroll
    for (int e = 1; e < 16; ++e) if (pr[e] > bv) { bv = pr[e]; bi = e; }
    float sv = -1.0f; int si = 0;
    #pragma unroll
    for (int e = 0; e < 16; ++e) if (e != bi && pr[e] > sv) { sv = pr[e]; si = e; }
    float ts = fmaxf(fabsf(bv) + fabsf(sv), 1e-12f);
    out[OFF_TP + (size_t)token * 2 + 0] = bv / ts;
    out[OFF_TP + (size_t)token * 2 + 1] = sv / ts;
    out[OFF_TI + (size_t)token * 2 + 0] = (float)bi;
    out[OFF_TI + (size_t)token * 2 + 1] = (float)si;
}

extern "C" void kernel_launch(void* const* d_in, const int* in_sizes, int n_in,
                              void* d_out, int out_size, void* d_ws, size_t ws_size,
                              hipStream_t stream) {
    const float* xg  = (const float*)d_in[0];
    const float* w1a = (const float*)d_in[1];
    const float* b1a = (const float*)d_in[2];
    const float* w2a = (const float*)d_in[3];
    const float* b2a = (const float*)d_in[4];
    const float* w1p = (const float*)d_in[5];
    const float* b1p = (const float*)d_in[6];
    const float* w2p = (const float*)d_in[7];
    const float* b2p = (const float*)d_in[8];
    const float* ent = (const float*)d_in[9];
    float* out = (float*)d_out;

    if (ws_size >= (size_t)4 * 1024 * 1024) {
        _Float16* wt = (_Float16*)d_ws;
        qir_wtrans<<<1024, 256, 0, stream>>>(w1a, w1p, wt, out);
        qir_gemm<<<512, 512, 65536, stream>>>(xg, wt, b1a, w2a, b2a,
                                              b1p, w2p, b2p, out);
    } else {
        qir_mlp<<<NTOK / 64, 512, 0, stream>>>(xg, w1a, b1a, w2a, b2a,
                                               w1p, b1p, w2p, b2p, out);
    }
    qir_epilogue<<<NTOK / 256, 256, 0, stream>>>(ent, out);
}